// Round 7
// baseline (358.241 us; speedup 1.0000x reference)
//
#include <hip/hip_runtime.h>
#include <hip/hip_bf16.h>
#include <stdint.h>

#define N_NODES 100000
#define N_EDGES 1600000
#define CH 128
#define N_REL 8
#define N_PAD 100096            // N_NODES rounded up to multiple of 128
#define N_KEYS (N_NODES * N_REL)

#define NBKT 782                // N_PAD / 128 mega buckets (= mega grid)
#define NGRP 98                 // coarse groups of 1024 rows (8 mega buckets each)
#define NCHUNK 782              // edge chunks (one per prep block)
#define CHUNK_E 2048            // edges per chunk (256 thr x 8)
#define GSLOT 64                // per-(chunk,group) cap; mean 20.9, sigma 4.55 ->
                                // +9.5 sigma, overflow P ~ 1e-15 (never trips)
#define PERM_LDS_CAP 4096       // per-bucket edges ~2046 +- 45 -> 45-sigma margin

using frag_ab = __attribute__((ext_vector_type(8))) short;  // 8 bf16
using frag_cd = __attribute__((ext_vector_type(4))) float;  // 4 fp32

__device__ __forceinline__ short f2bs(float f) {
    union { __hip_bfloat16 h; short s; } u;
    u.h = __float2bfloat16(f);
    return u.s;
}

__device__ __forceinline__ uint32_t pack2bf(float a, float b) {
    union { __hip_bfloat16 h; unsigned short s; } ua, ub;
    ua.h = __float2bfloat16(a); ub.h = __float2bfloat16(b);
    return (uint32_t)ua.s | ((uint32_t)ub.s << 16);
}

__device__ __forceinline__ float bf_lo(uint32_t u) { return __uint_as_float(u << 16); }
__device__ __forceinline__ float bf_hi(uint32_t u) { return __uint_as_float(u & 0xffff0000u); }

// ======================= prologue: coarse 98-way partition =======================
// R7: R6 measured that the cost drivers are (a) scattered 4B stores (line-RMW)
// in prep and (b) sparse slot enumeration in mega phase 0. Fix: bin to 98 fat
// groups (1024 rows). Per chunk a group cell holds ~21 entries -> ~84B
// contiguous write runs (8x fewer lines, no sub-line waste), and mega reads
// one 256B cell per wave, coalesced, shared by its 8 sibling blocks (L2-warm).
// Entry: src<<13 | (dst&1023)<<3 | rel. Zero global atomics (R6 lesson kept).

__global__ __launch_bounds__(256)
void prep_kernel(const int* __restrict__ ei, const int* __restrict__ et,
                 uint32_t* __restrict__ ents, int* __restrict__ lens,
                 const float* __restrict__ x, short* __restrict__ xb,
                 const float* __restrict__ root, const float* __restrict__ W,
                 short* __restrict__ Bsw) {
    __shared__ int hist[NGRP];
    const int tid = threadIdx.x;
    const int c = blockIdx.x;
    const int g = blockIdx.x * 256 + tid;

    // --- edge partition: blocks 0..NCHUNK-1 bin their 2048-edge chunk ---
    if (c < NCHUNK) {
        if (tid < NGRP) hist[tid] = 0;
        __syncthreads();
#pragma unroll
        for (int j = 0; j < 8; ++j) {
            const int e = c * CHUNK_E + j * 256 + tid;   // coalesced ei/et reads
            if (e < N_EDGES) {
                const int dst = ei[N_EDGES + e];
                const int src = ei[e];
                const int r = et[e];
                const int gr = dst >> 10;
                const int pos = atomicAdd(&hist[gr], 1);  // LDS atomic
                if (pos < GSLOT)
                    ents[((size_t)c * NGRP + gr) * GSLOT + pos] =
                        ((uint32_t)src << 13) | ((uint32_t)(dst & 1023) << 3) | (uint32_t)r;
            }
        }
        __syncthreads();
        if (tid < NGRP) {
            int n = hist[tid];
            lens[(size_t)c * NGRP + tid] = (n > GSLOT) ? GSLOT : n;
        }
    }

    // --- xconv: x fp32 -> bf16, 8 elements per thread (grid covers exactly) ---
    if (g < N_NODES * CH / 8) {
        const float4* xp = (const float4*)x;
        float4 a = xp[(size_t)g * 2], bb = xp[(size_t)g * 2 + 1];
        frag_ab f;
        f[0] = f2bs(a.x); f[1] = f2bs(a.y); f[2] = f2bs(a.z); f[3] = f2bs(a.w);
        f[4] = f2bs(bb.x); f[5] = f2bs(bb.y); f[6] = f2bs(bb.z); f[7] = f2bs(bb.w);
        *(frag_ab*)(xb + (size_t)g * 8) = f;
    }

    // --- bconv: swizzled bf16 B, entry = ((ks*4+quad)*8+ct)*16+m16 ---
    if (g < 9 * 2048) {
        int chunk = g >> 11, entry = g & 2047;
        int m16 = entry & 15, ct = (entry >> 4) & 7, quad = (entry >> 7) & 3, ks = entry >> 9;
        const float* src = (chunk == 0) ? root : W + (size_t)(chunk - 1) * CH * CH;
        int col = ct * 16 + m16, kb = ks * 32 + quad * 8;
        frag_ab f;
#pragma unroll
        for (int j = 0; j < 8; ++j) f[j] = f2bs(src[(size_t)(kb + j) * CH + col]);
        *(frag_ab*)(Bsw + (size_t)g * 8) = f;
    }
}

// ======================= MEGA: filter-compact + bin + aggregate + GEMM =======================
// One block = 128 output rows = sub-bucket (b&7) of coarse group G = b>>3.
// Phase 0: ONE coalesced pass over G's cells (wave = one 256B cell), dst-range
//          filter, ballot-aggregated compaction into LDS stage[] (one LDS atomic
//          per wave per hit-mask). Then hist/scan/scatter over the ~2046 compact
//          LDS entries (cheap). R6's double sparse-slot walk is gone.
// Phase r: aggregate relation r into the 32KB swizzled A-tile (4-lane groups,
//          64B/lane, unroll x2, branch-free perm_lds), then MFMA chunk r+1.
#define ACC_U4(U, B)                                            \
    do {                                                        \
        a[(B)+0] += bf_lo((U).x); a[(B)+1] += bf_hi((U).x);     \
        a[(B)+2] += bf_lo((U).y); a[(B)+3] += bf_hi((U).y);     \
        a[(B)+4] += bf_lo((U).z); a[(B)+5] += bf_hi((U).z);     \
        a[(B)+6] += bf_lo((U).w); a[(B)+7] += bf_hi((U).w);     \
    } while (0)

__global__ __launch_bounds__(512, 4)
void rgcn_mega(const int* __restrict__ lens, const uint32_t* __restrict__ ents,
               const short* __restrict__ xb, const short* __restrict__ Bsw,
               const float* __restrict__ bias, float* __restrict__ out) {
    __shared__ short Ash[128 * 128];        // 32 KB A-tile; aliased in phase 0
    __shared__ int perm_lds[PERM_LDS_CAP];  // 16 KB sorted src ids
    __shared__ uint32_t stage[PERM_LDS_CAP];// 16 KB compact raw entries
    __shared__ int lends[1025];             // local segment ends; lends[0] = 0
    __shared__ int lens_l[NCHUNK];          // this group's per-chunk counts
    __shared__ int ncomp;
    int* hist   = (int*)Ash;                // [1024]  (alias, phase 0 only)
    int* cursor = (int*)Ash + 1024;         // [1024]
    int* shl    = (int*)Ash + 2048;         // [512]

    const int tid = threadIdx.x;
    const int wave = tid >> 6, lane = tid & 63;
    const int m16 = lane & 15, quad = lane >> 4;
    const int wm = wave >> 2, wn = wave & 3;     // wave tile: 64 rows x 32 cols
    const int b = blockIdx.x;
    const int G = b >> 3, sb = b & 7;            // parent group, sub-bucket
    const long B0 = (long)b * 128;

    // ---- phase 0a: per-chunk counts + filter-compact into stage[] ----
    for (int i = tid; i < NCHUNK; i += 512) lens_l[i] = lens[(size_t)i * NGRP + G];
    hist[tid] = 0; hist[tid + 512] = 0;
    if (tid == 0) { ncomp = 0; perm_lds[0] = 0; }
    __syncthreads();
    for (int j = tid; j < NCHUNK * GSLOT; j += 512) {
        const int c = j >> 6, i = j & (GSLOT - 1);   // wave = one 256B cell
        uint32_t v = 0;
        bool hit = false;
        if (i < lens_l[c]) {
            v = ents[((size_t)c * NGRP + G) * GSLOT + i];
            hit = (((v >> 10) & 7) == (uint32_t)sb);
        }
        const unsigned long long m = __ballot(hit);
        if (m) {
            const int leader = __ffsll((long long)m) - 1;
            int base = 0;
            if (lane == leader) base = atomicAdd(&ncomp, __popcll(m));
            base = __shfl(base, leader);
            if (hit) {
                const int pos = base + __popcll(m & ((1ULL << lane) - 1ULL));
                if (pos < PERM_LDS_CAP) stage[pos] = v;
            }
        }
    }
    __syncthreads();
    int nloc = ncomp; if (nloc > PERM_LDS_CAP) nloc = PERM_LDS_CAP;
    // ---- phase 0b: histogram over compact entries (key = localrow*8 + rel) ----
    for (int i = tid; i < nloc; i += 512) {
        const uint32_t v = stage[i];
        atomicAdd(&hist[(((v >> 3) & 127) << 3) | (v & 7)], 1);
    }
    __syncthreads();
    // ---- phase 0c: scan (pair-sums, Hillis-Steele over 512) ----
    const int h0 = hist[2 * tid], h1 = hist[2 * tid + 1];
    const int s2 = h0 + h1;
    shl[tid] = s2;
    __syncthreads();
    for (int st = 1; st < 512; st <<= 1) {
        int u = (tid >= st) ? shl[tid - st] : 0;
        __syncthreads();
        shl[tid] += u;
        __syncthreads();
    }
    const int excl = shl[tid] - s2;
    cursor[2 * tid]     = excl;
    cursor[2 * tid + 1] = excl + h0;
    if (tid == 0) lends[0] = 0;
    {   // clamp so hot-loop indices stay < PERM_LDS_CAP (branch-free reads)
        int e1 = excl + h0, e2 = excl + h0 + h1;
        lends[1 + 2 * tid] = (e1 > PERM_LDS_CAP) ? PERM_LDS_CAP : e1;
        lends[2 + 2 * tid] = (e2 > PERM_LDS_CAP) ? PERM_LDS_CAP : e2;
    }
    __syncthreads();
    // ---- phase 0d: scatter into LDS perm (src only) ----
    for (int i = tid; i < nloc; i += 512) {
        const uint32_t v = stage[i];
        const int pos = atomicAdd(&cursor[(((v >> 3) & 127) << 3) | (v & 7)], 1);
        if (pos < PERM_LDS_CAP) perm_lds[pos] = (int)(v >> 13);
    }

    // ---- chunk 0 (root): A direct from global xb; overlaps the scatter tail ----
    float bcol[2];
#pragma unroll
    for (int ct = 0; ct < 2; ++ct) bcol[ct] = bias[wn * 32 + ct * 16 + m16];

    frag_cd acc[4][2];
#pragma unroll
    for (int mt = 0; mt < 4; ++mt)
#pragma unroll
        for (int ct = 0; ct < 2; ++ct) acc[mt][ct] = (frag_cd){0.f, 0.f, 0.f, 0.f};

#pragma unroll
    for (int ks = 0; ks < 4; ++ks) {
        frag_ab af[4];
#pragma unroll
        for (int mt = 0; mt < 4; ++mt)
            af[mt] = *(const frag_ab*)(xb + (B0 + wm * 64 + mt * 16 + m16) * CH + ks * 32 + quad * 8);
#pragma unroll
        for (int ct = 0; ct < 2; ++ct) {
            frag_ab bf = *(const frag_ab*)(Bsw + (size_t)((((ks * 4 + quad) * 8) + wn * 2 + ct) * 16 + m16) * 8);
#pragma unroll
            for (int mt = 0; mt < 4; ++mt)
                acc[mt][ct] = __builtin_amdgcn_mfma_f32_16x16x32_bf16(af[mt], bf, acc[mt][ct], 0, 0, 0);
        }
    }
    __syncthreads();   // phase 0 aliases dead, Ash free

    // ---- relation loop ----
    const int lrow = tid >> 2;                     // 4-lane group -> one dst row
    const int q4 = tid & 3;
    const uint32_t ch64 = (uint32_t)q4 << 6;       // this lane's 64B channel slice
    const char* xbp = (const char*)xb;
    char* drow = (char*)Ash + lrow * 256;
    const int swz = lrow & 7;

    for (int r = 0; r < N_REL; ++r) {
        const int keyL = lrow * 8 + r;
        const int s = lends[keyL];
        const int e = lends[keyL + 1];
        float a[32];
#pragma unroll
        for (int i = 0; i < 32; ++i) a[i] = 0.f;
        int p0 = perm_lds[(s < e) ? s : 0];
        int p1 = perm_lds[(s + 1 < e) ? s + 1 : ((s < e) ? s : 0)];
        for (int k = s; k < e; k += 2) {
            const char* c0 = xbp + (((size_t)(uint32_t)p0 << 8) | ch64);
            const char* c1 = xbp + (((size_t)(uint32_t)p1 << 8) | ch64);
            const uint4 u0 = *(const uint4*)(c0);
            const uint4 u1 = *(const uint4*)(c0 + 16);
            const uint4 u2 = *(const uint4*)(c0 + 32);
            const uint4 u3 = *(const uint4*)(c0 + 48);
            const uint4 u4 = *(const uint4*)(c1);
            const uint4 u5 = *(const uint4*)(c1 + 16);
            const uint4 u6 = *(const uint4*)(c1 + 32);
            const uint4 u7 = *(const uint4*)(c1 + 48);
            const bool two = (k + 1 < e);
            const int kn = k + 2;
            p0 = perm_lds[(kn < e) ? kn : 0];
            p1 = perm_lds[(kn + 1 < e) ? kn + 1 : 0];
            ACC_U4(u0, 0); ACC_U4(u1, 8); ACC_U4(u2, 16); ACC_U4(u3, 24);
            if (two) { ACC_U4(u4, 0); ACC_U4(u5, 8); ACC_U4(u6, 16); ACC_U4(u7, 24); }
        }
        const int c = e - s;
        const float sc = (c > 1) ? (1.0f / (float)c) : 1.0f;
#pragma unroll
        for (int t = 0; t < 4; ++t) {
            uint4 w;
            w.x = pack2bf(a[t * 8 + 0] * sc, a[t * 8 + 1] * sc);
            w.y = pack2bf(a[t * 8 + 2] * sc, a[t * 8 + 3] * sc);
            w.z = pack2bf(a[t * 8 + 4] * sc, a[t * 8 + 5] * sc);
            w.w = pack2bf(a[t * 8 + 6] * sc, a[t * 8 + 7] * sc);
            *(uint4*)(drow + (((q4 * 4 + t) ^ swz) << 4)) = w;   // swizzled A-tile write
        }
        __syncthreads();
        // ---- MFMA chunk r+1: A from LDS (swizzled ds_read_b128), B from L2-hot Bsw ----
        const short* Bc = Bsw + (size_t)(r + 1) * 2048 * 8;
#pragma unroll
        for (int ks = 0; ks < 4; ++ks) {
            frag_ab af[4];
#pragma unroll
            for (int mt = 0; mt < 4; ++mt) {
                const int lr = wm * 64 + mt * 16 + m16;
                af[mt] = *(const frag_ab*)((const char*)Ash + lr * 256 + (((ks * 4 + quad) ^ (lr & 7)) << 4));
            }
#pragma unroll
            for (int ct = 0; ct < 2; ++ct) {
                frag_ab bf = *(const frag_ab*)(Bc + (size_t)((((ks * 4 + quad) * 8) + wn * 2 + ct) * 16 + m16) * 8);
#pragma unroll
                for (int mt = 0; mt < 4; ++mt)
                    acc[mt][ct] = __builtin_amdgcn_mfma_f32_16x16x32_bf16(af[mt], bf, acc[mt][ct], 0, 0, 0);
            }
        }
        __syncthreads();
    }

    // ---- epilogue ----
#pragma unroll
    for (int mt = 0; mt < 4; ++mt) {
#pragma unroll
        for (int ct = 0; ct < 2; ++ct) {
            const long row0 = B0 + wm * 64 + mt * 16 + quad * 4;
            const int col = wn * 32 + ct * 16 + m16;
#pragma unroll
            for (int rg = 0; rg < 4; ++rg) {
                const long rr = row0 + rg;
                if (rr < N_NODES) out[rr * CH + col] = acc[mt][ct][rg] + bcol[ct];
            }
        }
    }
}

// ======================= fallback tiers (round-1 code) =======================

__global__ void count_rd_kernel(const int* __restrict__ ei, const int* __restrict__ et,
                                int* __restrict__ cnt) {
    int e = blockIdx.x * 256 + threadIdx.x;
    if (e < N_EDGES) {
        int dst = ei[N_EDGES + e];
        int r = et[e];
        atomicAdd(&cnt[r * N_NODES + dst], 1);
    }
}

__global__ void scatter_kernel(const int* __restrict__ ei, const int* __restrict__ et,
                               const float* __restrict__ x, float* __restrict__ sums,
                               int rel) {
    int gid = (blockIdx.x * 256 + threadIdx.x) >> 5;
    int lane = threadIdx.x & 31;
    int ngroups = gridDim.x * 8;
    for (int e = gid; e < N_EDGES; e += ngroups) {
        if (et[e] != rel) continue;
        int src = ei[e];
        int dst = ei[N_EDGES + e];
        float4 v = ((const float4*)(x + (size_t)src * CH))[lane];
        float* s = sums + (size_t)dst * CH + (size_t)lane * 4;
        atomicAdd(s + 0, v.x);
        atomicAdd(s + 1, v.y);
        atomicAdd(s + 2, v.z);
        atomicAdd(s + 3, v.w);
    }
}

__global__ __launch_bounds__(256, 2)
void gemm_kernel(const float* __restrict__ A, const float* __restrict__ B,
                 const float* __restrict__ bias, const int* __restrict__ cnt,
                 float* __restrict__ out, int accumulate) {
    const int wave = threadIdx.x >> 6;
    const int lane = threadIdx.x & 63;
    const int m16 = lane & 15;
    const int quad = lane >> 4;

    frag_ab bfrag[4][8];
#pragma unroll
    for (int ks = 0; ks < 4; ++ks) {
        const int kb = ks * 32 + quad * 8;
#pragma unroll
        for (int ct = 0; ct < 8; ++ct) {
            const int col = ct * 16 + m16;
            frag_ab f;
#pragma unroll
            for (int j = 0; j < 8; ++j)
                f[j] = f2bs(B[(size_t)(kb + j) * CH + col]);
            bfrag[ks][ct] = f;
        }
    }

    const int nstrips = (N_NODES + 63) / 64;
    for (int strip = blockIdx.x; strip < nstrips; strip += gridDim.x) {
        const int row = strip * 64 + wave * 16 + m16;
        const bool valid = row < N_NODES;
        float scale = 1.0f;
        if (cnt != nullptr && valid) {
            int c = cnt[row];
            if (c > 1) scale = 1.0f / (float)c;
        }
        const float4* arow = (const float4*)(A + (size_t)(valid ? row : 0) * CH);
        frag_cd acc[8];
#pragma unroll
        for (int ct = 0; ct < 8; ++ct) acc[ct] = (frag_cd){0.f, 0.f, 0.f, 0.f};
#pragma unroll
        for (int ks = 0; ks < 4; ++ks) {
            float4 a0 = arow[ks * 8 + quad * 2];
            float4 a1 = arow[ks * 8 + quad * 2 + 1];
            frag_ab af;
            af[0] = f2bs(a0.x * scale); af[1] = f2bs(a0.y * scale);
            af[2] = f2bs(a0.z * scale); af[3] = f2bs(a0.w * scale);
            af[4] = f2bs(a1.x * scale); af[5] = f2bs(a1.y * scale);
            af[6] = f2bs(a1.z * scale); af[7] = f2bs(a1.w * scale);
#pragma unroll
            for (int ct = 0; ct < 8; ++ct)
                acc[ct] = __builtin_amdgcn_mfma_f32_16x16x32_bf16(af, bfrag[ks][ct], acc[ct], 0, 0, 0);
        }
        const int obase = strip * 64 + wave * 16 + quad * 4;
#pragma unroll
        for (int ct = 0; ct < 8; ++ct) {
            const int col = ct * 16 + m16;
#pragma unroll
            for (int rg = 0; rg < 4; ++rg) {
                const int r = obase + rg;
                if (r < N_NODES) {
                    const size_t idx = (size_t)r * CH + col;
                    if (accumulate) out[idx] += acc[ct][rg];
                    else out[idx] = acc[ct][rg] + bias[col];
                }
            }
        }
    }
}

__global__ void edge_transform_kernel(const int* __restrict__ ei, const int* __restrict__ et,
                                      const float* __restrict__ x, const float* __restrict__ W,
                                      const int* __restrict__ cnt, float* __restrict__ out) {
    __shared__ float xs[CH];
    const int tid = threadIdx.x;
    for (int e = blockIdx.x; e < N_EDGES; e += gridDim.x) {
        const int src = ei[e];
        const int dst = ei[N_EDGES + e];
        const int r = et[e];
        __syncthreads();
        xs[tid] = x[(size_t)src * CH + tid];
        __syncthreads();
        const int c = cnt[r * N_NODES + dst];
        const float scale = (c > 1) ? (1.0f / (float)c) : 1.0f;
        const float* Wr = W + (size_t)r * CH * CH;
        float acc = 0.f;
#pragma unroll 8
        for (int k = 0; k < CH; ++k) acc += xs[k] * Wr[(size_t)k * CH + tid];
        atomicAdd(&out[(size_t)dst * CH + tid], acc * scale);
    }
}

// ======================= launch =======================

static inline size_t al512(size_t x) { return (x + 511) & ~(size_t)511; }

extern "C" void kernel_launch(void* const* d_in, const int* in_sizes, int n_in,
                              void* d_out, int out_size, void* d_ws, size_t ws_size,
                              hipStream_t stream) {
    const float* x    = (const float*)d_in[0];
    const int*   ei   = (const int*)d_in[1];   // [2, E]: row0=src, row1=dst
    const int*   et   = (const int*)d_in[2];   // [E]
    const float* W    = (const float*)d_in[3]; // [R,128,128]
    const float* root = (const float*)d_in[4]; // [128,128]
    const float* bias = (const float*)d_in[5]; // [128]
    float* out = (float*)d_out;

    // ---- tier-1 workspace layout (coarse 98-way partition) ----
    size_t o = 0;
    const size_t o_ents = o; o += al512((size_t)NCHUNK * NGRP * GSLOT * 4);  // 19.6 MB
    const size_t o_lens = o; o += al512((size_t)NCHUNK * NGRP * 4);          // 307 KB
    const size_t o_bsw  = o; o += al512((size_t)9 * 2048 * 16);
    const size_t o_xb   = o; o += al512((size_t)N_PAD * CH * 2);             // 25.6 MB
    const size_t need_t1 = o;

    const size_t cnt_bytes = (size_t)N_REL * N_NODES * sizeof(int);
    const size_t cnt_rsv   = al512(cnt_bytes);
    const size_t sums51    = (size_t)N_NODES * CH * sizeof(float);

    char* ws = (char*)d_ws;
    if (ws_size >= need_t1) {
        uint32_t* ents = (uint32_t*)(ws + o_ents);
        int*      lens = (int*)(ws + o_lens);
        short*    Bsw  = (short*)(ws + o_bsw);
        short*    xb   = (short*)(ws + o_xb);

        prep_kernel<<<(N_NODES * CH / 8 + 255) / 256, 256, 0, stream>>>(
            ei, et, ents, lens, x, xb, root, W, Bsw);
        rgcn_mega<<<NBKT, 512, 0, stream>>>(lens, ents, xb, Bsw, bias, out);
    } else if (ws_size >= cnt_rsv + sums51) {
        int*   cnt  = (int*)d_ws;
        float* sums = (float*)((char*)d_ws + cnt_rsv);
        hipMemsetAsync(cnt, 0, cnt_bytes, stream);
        count_rd_kernel<<<(N_EDGES + 255) / 256, 256, 0, stream>>>(ei, et, cnt);
        gemm_kernel<<<512, 256, 0, stream>>>(x, root, bias, nullptr, out, 0);
        for (int r = 0; r < N_REL; ++r) {
            hipMemsetAsync(sums, 0, sums51, stream);
            scatter_kernel<<<6400, 256, 0, stream>>>(ei, et, x, sums, r);
            gemm_kernel<<<512, 256, 0, stream>>>(sums, W + (size_t)r * CH * CH,
                                                 nullptr, cnt + (size_t)r * N_NODES, out, 1);
        }
    } else {
        int* cnt = (int*)d_ws;
        hipMemsetAsync(cnt, 0, cnt_bytes, stream);
        count_rd_kernel<<<(N_EDGES + 255) / 256, 256, 0, stream>>>(ei, et, cnt);
        gemm_kernel<<<512, 256, 0, stream>>>(x, root, bias, nullptr, out, 0);
        edge_transform_kernel<<<65536, CH, 0, stream>>>(ei, et, x, W, cnt, out);
    }
}

// Round 8
// 287.082 us; speedup vs baseline: 1.2479x; 1.2479x over previous
//
#include <hip/hip_runtime.h>
#include <hip/hip_bf16.h>
#include <stdint.h>

#define N_NODES 100000
#define N_EDGES 1600000
#define CH 128
#define N_REL 8
#define N_PAD 100096            // N_NODES rounded up to multiple of 128
#define N_KEYS (N_NODES * N_REL)

#define NBKT 782                // N_PAD / 128 buckets (= bin/fused grid)
#define NCHUNK 782              // edge chunks (one per prep block)
#define CHUNK_E 2048            // edges per chunk (256 thr x 8)
#define CELL_CAP 20             // per-(chunk,bucket) cap; Poisson lam=2.62 ->
                                // P(>20) ~ 8e-13/cell, ~5e-7 overall
#define NSLOT (NBKT * CELL_CAP) // 15640 slots per chunk
#define SENT 0xFFFFFFFFu
#define PERM_LDS_CAP 4096       // per-bucket edges ~2046 +- 45 -> 45-sigma margin

using frag_ab = __attribute__((ext_vector_type(8))) short;  // 8 bf16
using frag_cd = __attribute__((ext_vector_type(4))) float;  // 4 fp32

__device__ __forceinline__ short f2bs(float f) {
    union { __hip_bfloat16 h; short s; } u;
    u.h = __float2bfloat16(f);
    return u.s;
}

__device__ __forceinline__ uint32_t pack2bf(float a, float b) {
    union { __hip_bfloat16 h; unsigned short s; } ua, ub;
    ua.h = __float2bfloat16(a); ub.h = __float2bfloat16(b);
    return (uint32_t)ua.s | ((uint32_t)ub.s << 16);
}

__device__ __forceinline__ float bf_lo(uint32_t u) { return __uint_as_float(u << 16); }
__device__ __forceinline__ float bf_hi(uint32_t u) { return __uint_as_float(u & 0xffff0000u); }

// ======================= prep: LDS-staged chunk binning =======================
// R8: R6/R7 measured prep stuck at ~120us because per-edge global stores are
// scattered 4B line-RMWs REGARDLESS of eventual layout (within one wave store,
// 64 edges hit ~50 cells). Fix: bin the whole chunk in LDS (sentinel-filled
// cell array, LDS atomics), then write the 62.5KB region out LINEARLY --
// fully-coalesced full-line stores. Zero global atomics, zero memsets.
// Entry: src<<10 | (dst&127)<<3 | rel.

__global__ __launch_bounds__(256)
void prep_kernel(const int* __restrict__ ei, const int* __restrict__ et,
                 uint32_t* __restrict__ ents,
                 const float* __restrict__ x, short* __restrict__ xb,
                 const float* __restrict__ root, const float* __restrict__ W,
                 short* __restrict__ Bsw) {
    __shared__ uint32_t cell[NSLOT];   // 62.5 KB
    __shared__ int cur[NBKT];
    const int tid = threadIdx.x;
    const int c = blockIdx.x;
    const int g = blockIdx.x * 256 + tid;

    if (c < NCHUNK) {
        for (int i = tid; i < NSLOT; i += 256) cell[i] = SENT;
        for (int i = tid; i < NBKT; i += 256) cur[i] = 0;
        __syncthreads();
#pragma unroll
        for (int j = 0; j < 8; ++j) {
            const int e = c * CHUNK_E + j * 256 + tid;   // coalesced ei/et reads
            if (e < N_EDGES) {
                const int dst = ei[N_EDGES + e];
                const int src = ei[e];
                const int r = et[e];
                const int b = dst >> 7;
                const int pos = atomicAdd(&cur[b], 1);   // LDS atomic: cycles
                if (pos < CELL_CAP)
                    cell[b * CELL_CAP + pos] =
                        ((uint32_t)src << 10) | ((uint32_t)(dst & 127) << 3) | (uint32_t)r;
            }
        }
        __syncthreads();
        uint32_t* dst_g = ents + (size_t)c * NSLOT;      // linear coalesced write-out
        for (int i = tid; i < NSLOT; i += 256) dst_g[i] = cell[i];
    }

    // --- xconv: x fp32 -> bf16, 8 elements per thread (grid covers exactly) ---
    if (g < N_NODES * CH / 8) {
        const float4* xp = (const float4*)x;
        float4 a = xp[(size_t)g * 2], bb = xp[(size_t)g * 2 + 1];
        frag_ab f;
        f[0] = f2bs(a.x); f[1] = f2bs(a.y); f[2] = f2bs(a.z); f[3] = f2bs(a.w);
        f[4] = f2bs(bb.x); f[5] = f2bs(bb.y); f[6] = f2bs(bb.z); f[7] = f2bs(bb.w);
        *(frag_ab*)(xb + (size_t)g * 8) = f;
    }

    // --- bconv: swizzled bf16 B, entry = ((ks*4+quad)*8+ct)*16+m16 ---
    if (g < 9 * 2048) {
        int chunk = g >> 11, entry = g & 2047;
        int m16 = entry & 15, ct = (entry >> 4) & 7, quad = (entry >> 7) & 3, ks = entry >> 9;
        const float* src = (chunk == 0) ? root : W + (size_t)(chunk - 1) * CH * CH;
        int col = ct * 16 + m16, kb = ks * 32 + quad * 8;
        frag_ab f;
#pragma unroll
        for (int j = 0; j < 8; ++j) f[j] = f2bs(src[(size_t)(kb + j) * CH + col]);
        *(frag_ab*)(Bsw + (size_t)g * 8) = f;
    }
}

// ======================= bin: one block per bucket =======================
// Reads its OWN bucket's 782 cells (80B full-line strided reads; each cell is
// read by exactly one block -- no sibling redundancy, the R7 mistake), ballot-
// compacts valid entries to LDS, then hist/scan/scatter -> global perm + local
// ends. R4 measured this kernel shape at ~15-20us.

__global__ __launch_bounds__(512)
void bin_kernel(const uint32_t* __restrict__ ents,
                int* __restrict__ perm_g, int* __restrict__ ends_g) {
    __shared__ uint32_t stage[PERM_LDS_CAP];   // 16 KB compact entries
    __shared__ int hist[1024];
    __shared__ int cursor[1024];
    __shared__ int shl[512];
    __shared__ int ncomp;
    const int tid = threadIdx.x;
    const int lane = tid & 63;
    const int b = blockIdx.x;

    hist[tid] = 0; hist[tid + 512] = 0;
    if (tid == 0) ncomp = 0;
    __syncthreads();
    for (int j = tid; j < NCHUNK * CELL_CAP; j += 512) {
        const int c = j / CELL_CAP, i = j - c * CELL_CAP;
        const uint32_t v = ents[(size_t)c * NSLOT + b * CELL_CAP + i];
        const bool hit = (v != SENT);
        const unsigned long long m = __ballot(hit);
        if (m) {
            const int leader = __ffsll((long long)m) - 1;
            int base = 0;
            if (lane == leader) base = atomicAdd(&ncomp, __popcll(m));
            base = __shfl(base, leader);
            if (hit) {
                const int pos = base + __popcll(m & ((1ULL << lane) - 1ULL));
                if (pos < PERM_LDS_CAP) stage[pos] = v;
            }
        }
    }
    __syncthreads();
    int n = ncomp; if (n > PERM_LDS_CAP) n = PERM_LDS_CAP;
    for (int i = tid; i < n; i += 512) atomicAdd(&hist[stage[i] & 1023], 1);
    __syncthreads();
    const int h0 = hist[2 * tid], h1 = hist[2 * tid + 1];
    const int s2 = h0 + h1;
    shl[tid] = s2;
    __syncthreads();
    for (int st = 1; st < 512; st <<= 1) {   // Hillis-Steele inclusive over pair-sums
        int u = (tid >= st) ? shl[tid - st] : 0;
        __syncthreads();
        shl[tid] += u;
        __syncthreads();
    }
    const int excl = shl[tid] - s2;
    cursor[2 * tid]     = excl;
    cursor[2 * tid + 1] = excl + h0;
    {   // local (0-based) segment ends, clamped so fused LDS reads are in-bounds
        int e1 = excl + h0, e2 = excl + h0 + h1;
        ends_g[(size_t)b * 1024 + 2 * tid]     = (e1 > PERM_LDS_CAP) ? PERM_LDS_CAP : e1;
        ends_g[(size_t)b * 1024 + 2 * tid + 1] = (e2 > PERM_LDS_CAP) ? PERM_LDS_CAP : e2;
    }
    __syncthreads();
    for (int i = tid; i < n; i += 512) {
        const uint32_t v = stage[i];
        const int pos = atomicAdd(&cursor[v & 1023], 1);
        if (pos < PERM_LDS_CAP) perm_g[(size_t)b * PERM_LDS_CAP + pos] = (int)(v >> 10);
    }
}

// ======================= FUSED aggregate + GEMM =======================
// One block = 128 output rows = one bucket. Startup: copy this bucket's
// pre-binned perm (coalesced bulk copy, hidden under the root-chunk MFMA)
// into LDS -> gather loop index reads are branch-free LDS (R5's hot loop).
// Per relation r: aggregate into the 32KB swizzled A-tile (4-lane groups,
// 64B/lane, edge-unroll x2), then MFMA chunk r+1 into persistent accs.
// LDS 53.2KB -> 3 blocks/CU.
#define ACC_U4(U, B)                                            \
    do {                                                        \
        a[(B)+0] += bf_lo((U).x); a[(B)+1] += bf_hi((U).x);     \
        a[(B)+2] += bf_lo((U).y); a[(B)+3] += bf_hi((U).y);     \
        a[(B)+4] += bf_lo((U).z); a[(B)+5] += bf_hi((U).z);     \
        a[(B)+6] += bf_lo((U).w); a[(B)+7] += bf_hi((U).w);     \
    } while (0)

__global__ __launch_bounds__(512, 4)
void rgcn_fused(const int* __restrict__ ends_g, const int* __restrict__ perm_g,
                const short* __restrict__ xb, const short* __restrict__ Bsw,
                const float* __restrict__ bias, float* __restrict__ out) {
    __shared__ short Ash[128 * 128];        // 32 KB swizzled A-tile
    __shared__ int perm_lds[PERM_LDS_CAP];  // 16 KB
    __shared__ int lends[1025];             // local ends; lends[0] = 0
    const int tid = threadIdx.x;
    const int wave = tid >> 6, lane = tid & 63;
    const int m16 = lane & 15, quad = lane >> 4;
    const int wm = wave >> 2, wn = wave & 3;     // wave tile: 64 rows x 32 cols
    const int b = blockIdx.x;
    const long B0 = (long)b * 128;

    if (tid == 0) { lends[0] = 0; perm_lds[0] = 0; }
    for (int i = tid; i < 1024; i += 512) lends[1 + i] = ends_g[(size_t)b * 1024 + i];
    __syncthreads();
    const int nperm = lends[1024];
    for (int i = tid; i < nperm; i += 512) perm_lds[i] = perm_g[(size_t)b * PERM_LDS_CAP + i];

    // ---- chunk 0 (root): A direct from global xb; overlaps the perm copy ----
    float bcol[2];
#pragma unroll
    for (int ct = 0; ct < 2; ++ct) bcol[ct] = bias[wn * 32 + ct * 16 + m16];

    frag_cd acc[4][2];
#pragma unroll
    for (int mt = 0; mt < 4; ++mt)
#pragma unroll
        for (int ct = 0; ct < 2; ++ct) acc[mt][ct] = (frag_cd){0.f, 0.f, 0.f, 0.f};

#pragma unroll
    for (int ks = 0; ks < 4; ++ks) {
        frag_ab af[4];
#pragma unroll
        for (int mt = 0; mt < 4; ++mt)
            af[mt] = *(const frag_ab*)(xb + (B0 + wm * 64 + mt * 16 + m16) * CH + ks * 32 + quad * 8);
#pragma unroll
        for (int ct = 0; ct < 2; ++ct) {
            frag_ab bf = *(const frag_ab*)(Bsw + (size_t)((((ks * 4 + quad) * 8) + wn * 2 + ct) * 16 + m16) * 8);
#pragma unroll
            for (int mt = 0; mt < 4; ++mt)
                acc[mt][ct] = __builtin_amdgcn_mfma_f32_16x16x32_bf16(af[mt], bf, acc[mt][ct], 0, 0, 0);
        }
    }
    __syncthreads();   // perm_lds ready

    // ---- relation loop ----
    const int lrow = tid >> 2;                     // 4-lane group -> one dst row
    const int q4 = tid & 3;
    const uint32_t ch64 = (uint32_t)q4 << 6;       // this lane's 64B channel slice
    const char* xbp = (const char*)xb;
    char* drow = (char*)Ash + lrow * 256;
    const int swz = lrow & 7;

    for (int r = 0; r < N_REL; ++r) {
        const int keyL = lrow * 8 + r;
        const int s = lends[keyL];
        const int e = lends[keyL + 1];
        float a[32];
#pragma unroll
        for (int i = 0; i < 32; ++i) a[i] = 0.f;
        int p0 = perm_lds[(s < e) ? s : 0];
        int p1 = perm_lds[(s + 1 < e) ? s + 1 : ((s < e) ? s : 0)];
        for (int k = s; k < e; k += 2) {
            const char* c0 = xbp + (((size_t)(uint32_t)p0 << 8) | ch64);
            const char* c1 = xbp + (((size_t)(uint32_t)p1 << 8) | ch64);
            const uint4 u0 = *(const uint4*)(c0);
            const uint4 u1 = *(const uint4*)(c0 + 16);
            const uint4 u2 = *(const uint4*)(c0 + 32);
            const uint4 u3 = *(const uint4*)(c0 + 48);
            const uint4 u4 = *(const uint4*)(c1);
            const uint4 u5 = *(const uint4*)(c1 + 16);
            const uint4 u6 = *(const uint4*)(c1 + 32);
            const uint4 u7 = *(const uint4*)(c1 + 48);
            const bool two = (k + 1 < e);
            const int kn = k + 2;
            p0 = perm_lds[(kn < e) ? kn : 0];
            p1 = perm_lds[(kn + 1 < e) ? kn + 1 : 0];
            ACC_U4(u0, 0); ACC_U4(u1, 8); ACC_U4(u2, 16); ACC_U4(u3, 24);
            if (two) { ACC_U4(u4, 0); ACC_U4(u5, 8); ACC_U4(u6, 16); ACC_U4(u7, 24); }
        }
        const int c = e - s;
        const float sc = (c > 1) ? (1.0f / (float)c) : 1.0f;
#pragma unroll
        for (int t = 0; t < 4; ++t) {
            uint4 w;
            w.x = pack2bf(a[t * 8 + 0] * sc, a[t * 8 + 1] * sc);
            w.y = pack2bf(a[t * 8 + 2] * sc, a[t * 8 + 3] * sc);
            w.z = pack2bf(a[t * 8 + 4] * sc, a[t * 8 + 5] * sc);
            w.w = pack2bf(a[t * 8 + 6] * sc, a[t * 8 + 7] * sc);
            *(uint4*)(drow + (((q4 * 4 + t) ^ swz) << 4)) = w;   // swizzled A-tile write
        }
        __syncthreads();
        // ---- MFMA chunk r+1: A from LDS (swizzled ds_read_b128), B from L2-hot Bsw ----
        const short* Bc = Bsw + (size_t)(r + 1) * 2048 * 8;
#pragma unroll
        for (int ks = 0; ks < 4; ++ks) {
            frag_ab af[4];
#pragma unroll
            for (int mt = 0; mt < 4; ++mt) {
                const int lr = wm * 64 + mt * 16 + m16;
                af[mt] = *(const frag_ab*)((const char*)Ash + lr * 256 + (((ks * 4 + quad) ^ (lr & 7)) << 4));
            }
#pragma unroll
            for (int ct = 0; ct < 2; ++ct) {
                frag_ab bf = *(const frag_ab*)(Bc + (size_t)((((ks * 4 + quad) * 8) + wn * 2 + ct) * 16 + m16) * 8);
#pragma unroll
                for (int mt = 0; mt < 4; ++mt)
                    acc[mt][ct] = __builtin_amdgcn_mfma_f32_16x16x32_bf16(af[mt], bf, acc[mt][ct], 0, 0, 0);
            }
        }
        __syncthreads();
    }

    // ---- epilogue ----
#pragma unroll
    for (int mt = 0; mt < 4; ++mt) {
#pragma unroll
        for (int ct = 0; ct < 2; ++ct) {
            const long row0 = B0 + wm * 64 + mt * 16 + quad * 4;
            const int col = wn * 32 + ct * 16 + m16;
#pragma unroll
            for (int rg = 0; rg < 4; ++rg) {
                const long rr = row0 + rg;
                if (rr < N_NODES) out[rr * CH + col] = acc[mt][ct][rg] + bcol[ct];
            }
        }
    }
}

// ======================= fallback tiers (round-1 code) =======================

__global__ void count_rd_kernel(const int* __restrict__ ei, const int* __restrict__ et,
                                int* __restrict__ cnt) {
    int e = blockIdx.x * 256 + threadIdx.x;
    if (e < N_EDGES) {
        int dst = ei[N_EDGES + e];
        int r = et[e];
        atomicAdd(&cnt[r * N_NODES + dst], 1);
    }
}

__global__ void scatter_kernel(const int* __restrict__ ei, const int* __restrict__ et,
                               const float* __restrict__ x, float* __restrict__ sums,
                               int rel) {
    int gid = (blockIdx.x * 256 + threadIdx.x) >> 5;
    int lane = threadIdx.x & 31;
    int ngroups = gridDim.x * 8;
    for (int e = gid; e < N_EDGES; e += ngroups) {
        if (et[e] != rel) continue;
        int src = ei[e];
        int dst = ei[N_EDGES + e];
        float4 v = ((const float4*)(x + (size_t)src * CH))[lane];
        float* s = sums + (size_t)dst * CH + (size_t)lane * 4;
        atomicAdd(s + 0, v.x);
        atomicAdd(s + 1, v.y);
        atomicAdd(s + 2, v.z);
        atomicAdd(s + 3, v.w);
    }
}

__global__ __launch_bounds__(256, 2)
void gemm_kernel(const float* __restrict__ A, const float* __restrict__ B,
                 const float* __restrict__ bias, const int* __restrict__ cnt,
                 float* __restrict__ out, int accumulate) {
    const int wave = threadIdx.x >> 6;
    const int lane = threadIdx.x & 63;
    const int m16 = lane & 15;
    const int quad = lane >> 4;

    frag_ab bfrag[4][8];
#pragma unroll
    for (int ks = 0; ks < 4; ++ks) {
        const int kb = ks * 32 + quad * 8;
#pragma unroll
        for (int ct = 0; ct < 8; ++ct) {
            const int col = ct * 16 + m16;
            frag_ab f;
#pragma unroll
            for (int j = 0; j < 8; ++j)
                f[j] = f2bs(B[(size_t)(kb + j) * CH + col]);
            bfrag[ks][ct] = f;
        }
    }

    const int nstrips = (N_NODES + 63) / 64;
    for (int strip = blockIdx.x; strip < nstrips; strip += gridDim.x) {
        const int row = strip * 64 + wave * 16 + m16;
        const bool valid = row < N_NODES;
        float scale = 1.0f;
        if (cnt != nullptr && valid) {
            int c = cnt[row];
            if (c > 1) scale = 1.0f / (float)c;
        }
        const float4* arow = (const float4*)(A + (size_t)(valid ? row : 0) * CH);
        frag_cd acc[8];
#pragma unroll
        for (int ct = 0; ct < 8; ++ct) acc[ct] = (frag_cd){0.f, 0.f, 0.f, 0.f};
#pragma unroll
        for (int ks = 0; ks < 4; ++ks) {
            float4 a0 = arow[ks * 8 + quad * 2];
            float4 a1 = arow[ks * 8 + quad * 2 + 1];
            frag_ab af;
            af[0] = f2bs(a0.x * scale); af[1] = f2bs(a0.y * scale);
            af[2] = f2bs(a0.z * scale); af[3] = f2bs(a0.w * scale);
            af[4] = f2bs(a1.x * scale); af[5] = f2bs(a1.y * scale);
            af[6] = f2bs(a1.z * scale); af[7] = f2bs(a1.w * scale);
#pragma unroll
            for (int ct = 0; ct < 8; ++ct)
                acc[ct] = __builtin_amdgcn_mfma_f32_16x16x32_bf16(af, bfrag[ks][ct], acc[ct], 0, 0, 0);
        }
        const int obase = strip * 64 + wave * 16 + quad * 4;
#pragma unroll
        for (int ct = 0; ct < 8; ++ct) {
            const int col = ct * 16 + m16;
#pragma unroll
            for (int rg = 0; rg < 4; ++rg) {
                const int r = obase + rg;
                if (r < N_NODES) {
                    const size_t idx = (size_t)r * CH + col;
                    if (accumulate) out[idx] += acc[ct][rg];
                    else out[idx] = acc[ct][rg] + bias[col];
                }
            }
        }
    }
}

__global__ void edge_transform_kernel(const int* __restrict__ ei, const int* __restrict__ et,
                                      const float* __restrict__ x, const float* __restrict__ W,
                                      const int* __restrict__ cnt, float* __restrict__ out) {
    __shared__ float xs[CH];
    const int tid = threadIdx.x;
    for (int e = blockIdx.x; e < N_EDGES; e += gridDim.x) {
        const int src = ei[e];
        const int dst = ei[N_EDGES + e];
        const int r = et[e];
        __syncthreads();
        xs[tid] = x[(size_t)src * CH + tid];
        __syncthreads();
        const int c = cnt[r * N_NODES + dst];
        const float scale = (c > 1) ? (1.0f / (float)c) : 1.0f;
        const float* Wr = W + (size_t)r * CH * CH;
        float acc = 0.f;
#pragma unroll 8
        for (int k = 0; k < CH; ++k) acc += xs[k] * Wr[(size_t)k * CH + tid];
        atomicAdd(&out[(size_t)dst * CH + tid], acc * scale);
    }
}

// ======================= launch =======================

static inline size_t al512(size_t x) { return (x + 511) & ~(size_t)511; }

extern "C" void kernel_launch(void* const* d_in, const int* in_sizes, int n_in,
                              void* d_out, int out_size, void* d_ws, size_t ws_size,
                              hipStream_t stream) {
    const float* x    = (const float*)d_in[0];
    const int*   ei   = (const int*)d_in[1];   // [2, E]: row0=src, row1=dst
    const int*   et   = (const int*)d_in[2];   // [E]
    const float* W    = (const float*)d_in[3]; // [R,128,128]
    const float* root = (const float*)d_in[4]; // [128,128]
    const float* bias = (const float*)d_in[5]; // [128]
    float* out = (float*)d_out;

    // ---- tier-1 workspace layout ----
    size_t o = 0;
    const size_t o_ents = o; o += al512((size_t)NCHUNK * NSLOT * 4);          // 48.9 MB
    const size_t o_perm = o; o += al512((size_t)NBKT * PERM_LDS_CAP * 4);     // 12.8 MB
    const size_t o_ends = o; o += al512((size_t)NBKT * 1024 * 4);             // 3.2 MB
    const size_t o_bsw  = o; o += al512((size_t)9 * 2048 * 16);
    const size_t o_xb   = o; o += al512((size_t)N_PAD * CH * 2);              // 25.6 MB
    const size_t need_t1 = o;

    const size_t cnt_bytes = (size_t)N_REL * N_NODES * sizeof(int);
    const size_t cnt_rsv   = al512(cnt_bytes);
    const size_t sums51    = (size_t)N_NODES * CH * sizeof(float);

    char* ws = (char*)d_ws;
    if (ws_size >= need_t1) {
        uint32_t* ents   = (uint32_t*)(ws + o_ents);
        int*      perm_g = (int*)(ws + o_perm);
        int*      ends_g = (int*)(ws + o_ends);
        short*    Bsw    = (short*)(ws + o_bsw);
        short*    xb     = (short*)(ws + o_xb);

        prep_kernel<<<(N_NODES * CH / 8 + 255) / 256, 256, 0, stream>>>(
            ei, et, ents, x, xb, root, W, Bsw);
        bin_kernel<<<NBKT, 512, 0, stream>>>(ents, perm_g, ends_g);
        rgcn_fused<<<NBKT, 512, 0, stream>>>(ends_g, perm_g, xb, Bsw, bias, out);
    } else if (ws_size >= cnt_rsv + sums51) {
        int*   cnt  = (int*)d_ws;
        float* sums = (float*)((char*)d_ws + cnt_rsv);
        hipMemsetAsync(cnt, 0, cnt_bytes, stream);
        count_rd_kernel<<<(N_EDGES + 255) / 256, 256, 0, stream>>>(ei, et, cnt);
        gemm_kernel<<<512, 256, 0, stream>>>(x, root, bias, nullptr, out, 0);
        for (int r = 0; r < N_REL; ++r) {
            hipMemsetAsync(sums, 0, sums51, stream);
            scatter_kernel<<<6400, 256, 0, stream>>>(ei, et, x, sums, r);
            gemm_kernel<<<512, 256, 0, stream>>>(sums, W + (size_t)r * CH * CH,
                                                 nullptr, cnt + (size_t)r * N_NODES, out, 1);
        }
    } else {
        int* cnt = (int*)d_ws;
        hipMemsetAsync(cnt, 0, cnt_bytes, stream);
        count_rd_kernel<<<(N_EDGES + 255) / 256, 256, 0, stream>>>(ei, et, cnt);
        gemm_kernel<<<512, 256, 0, stream>>>(x, root, bias, nullptr, out, 0);
        edge_transform_kernel<<<65536, CH, 0, stream>>>(ei, et, x, W, cnt, out);
    }
}